// Round 4
// baseline (157.828 us; speedup 1.0000x reference)
//
#include <hip/hip_runtime.h>
#include <hip/hip_bf16.h>

// Problem constants (GPT2Attention classic): B=2, S=2048, E=1024, H=16, HD=64
#define B_ 2
#define S_ 2048
#define E_ 1024
#define H_ 16
#define HD_ 64
#define T_ (B_ * S_)  // 4096 tokens

typedef short bf16x8 __attribute__((ext_vector_type(8)));
typedef short bf16x4 __attribute__((ext_vector_type(4)));
typedef float f32x4 __attribute__((ext_vector_type(4)));

__device__ __forceinline__ short f2bf(float f) {
  union { float f; unsigned u; } v;
  v.f = f;
  unsigned r = v.u + 0x7fffu + ((v.u >> 16) & 1u);
  return (short)(r >> 16);
}

// V^T column permutation: storage col cc within a 64-key group holds key:
// cc bits: [5]=p, [4:3]=quad, [2]=hi, [1:0]=r  ->  key = (2p+hi)*16 + quad*4 + r
__device__ __forceinline__ int vperm_key(int cc) {
  return (cc & ~31) | (((cc >> 2) & 1) << 4) | (((cc >> 3) & 3) << 2) | (cc & 3);
}

// ---------------------------------------------------------------- kernel 1+2
// Merged: bid < 512 -> QKV projection; bid >= 512 -> proj_w fp32->bf16 convert.
// QKV: block = 64 tokens x 2 heads. Q pre-scaled by 0.125*log2(e) so attention
// can use exp2 directly. Q,K -> [B,H,S,HD]; V -> [B,H,HD,S] transposed+perm'd.
__global__ __launch_bounds__(256) void qkv_conv_kernel(
    const float* __restrict__ x,
    const float* __restrict__ wq, const float* __restrict__ bq,
    const float* __restrict__ wk, const float* __restrict__ bk,
    const float* __restrict__ wv, const float* __restrict__ bv,
    short* __restrict__ Q, short* __restrict__ K, short* __restrict__ V,
    const float* __restrict__ pw, short* __restrict__ pwb) {
  const int tid = threadIdx.x;
  if (blockIdx.x >= 512) {
    // ---- convert branch ----
    int i = ((blockIdx.x - 512) * 256 + tid) * 4;
    float4 f = *(const float4*)(pw + i);
    bf16x4 o;
    o[0] = f2bf(f.x); o[1] = f2bf(f.y); o[2] = f2bf(f.z); o[3] = f2bf(f.w);
    *(bf16x4*)(pwb + i) = o;
    return;
  }
  __shared__ short Xs[64][136];   // 64 tokens x 128 cols (2 heads)
  __shared__ short Ws[192][72];   // Wq|Wk|Wv rows
  __shared__ short Qt[64][68], Kt[64][68], Vt[64][68];

  const int bid = blockIdx.x;
  const int tb = bid >> 3, hg = bid & 7;   // token block, head group (2 heads)
  const int s0 = (tb * 64) & (S_ - 1);
  const int bb = (tb * 64) >> 11;          // batch index
  const int wave = tid >> 6, lane = tid & 63;
  const int lrow = lane & 15, quad = lane >> 4;

  // stage x slice: 64 rows x 128 fp32 cols -> bf16
#pragma unroll
  for (int i = 0; i < 8; i++) {
    int c = tid + 256 * i;             // float4 index in [0,2048)
    int row = c >> 5, col4 = c & 31;
    float4 f = *(const float4*)(x + ((long)(tb * 64 + row)) * E_ + hg * 128 + col4 * 4);
    bf16x4 o;
    o[0] = f2bf(f.x); o[1] = f2bf(f.y); o[2] = f2bf(f.z); o[3] = f2bf(f.w);
    *(bf16x4*)&Xs[row][col4 * 4] = o;
  }
  // stage weights
#pragma unroll
  for (int m = 0; m < 3; m++) {
    const float* w = (m == 0) ? wq : (m == 1) ? wk : wv;
#pragma unroll
    for (int i = 0; i < 4; i++) {
      int c = tid + 256 * i;           // float4 index in [0,1024)
      int row = m * 64 + (c >> 4), col = (c & 15) * 4;
      float4 f = *(const float4*)(w + (long)c * 4);
      bf16x4 o;
      o[0] = f2bf(f.x); o[1] = f2bf(f.y); o[2] = f2bf(f.z); o[3] = f2bf(f.w);
      *(bf16x4*)&Ws[row][col] = o;
    }
  }
  float bias[12];
#pragma unroll
  for (int nb = 0; nb < 12; nb++) {
    int sel = nb >> 2;
    int e = ((nb & 3) * 16) + lrow;
    bias[nb] = ((sel == 0) ? bq : (sel == 1) ? bk : bv)[e];
  }
  __syncthreads();

  bf16x8 bf0[12], bf1[12];
#pragma unroll
  for (int nb = 0; nb < 12; nb++) {
    bf0[nb] = *(bf16x8*)&Ws[nb * 16 + lrow][quad * 8];
    bf1[nb] = *(bf16x8*)&Ws[nb * 16 + lrow][32 + quad * 8];
  }

  const float QSCALE = 0.125f * 1.44269504089f;  // 1/sqrt(64) * log2(e)
  for (int hl = 0; hl < 2; hl++) {
    const int h = hg * 2 + hl;
    bf16x8 a0 = *(bf16x8*)&Xs[wave * 16 + lrow][hl * 64 + quad * 8];
    bf16x8 a1 = *(bf16x8*)&Xs[wave * 16 + lrow][hl * 64 + 32 + quad * 8];
#pragma unroll
    for (int nb = 0; nb < 12; nb++) {
      f32x4 acc = {0.f, 0.f, 0.f, 0.f};
      acc = __builtin_amdgcn_mfma_f32_16x16x32_bf16(a0, bf0[nb], acc, 0, 0, 0);
      acc = __builtin_amdgcn_mfma_f32_16x16x32_bf16(a1, bf1[nb], acc, 0, 0, 0);
      const int sel = nb >> 2;
      const float scale = (sel == 0) ? QSCALE : 1.0f;
      short (*ct)[68] = (sel == 0) ? Qt : (sel == 1) ? Kt : Vt;
#pragma unroll
      for (int r = 0; r < 4; r++) {
        ct[wave * 16 + quad * 4 + r][(nb & 3) * 16 + lrow] =
            f2bf((acc[r] + bias[nb]) * scale);
      }
    }
    __syncthreads();

    const int bh = bb * H_ + h;
    short* Qg = Q + ((long)bh * S_ + s0) * HD_;
    short* Kg = K + ((long)bh * S_ + s0) * HD_;
    short* Vg = V + (long)bh * HD_ * S_;
#pragma unroll
    for (int i = 0; i < 2; i++) {
      int c = tid + 256 * i;
      int row = c >> 3, col = (c & 7) * 8;
      *(bf16x8*)(Qg + (long)row * HD_ + col) = *(bf16x8*)&Qt[row][col];
      *(bf16x8*)(Kg + (long)row * HD_ + col) = *(bf16x8*)&Kt[row][col];
      bf16x8 vv;
#pragma unroll
      for (int j = 0; j < 8; j++) {
        int cc = col + j;
        vv[j] = Vt[vperm_key(cc)][row];  // row = d here
      }
      *(bf16x8*)(Vg + (long)row * S_ + s0 + col) = vv;
    }
    __syncthreads();
  }
}

// ---------------------------------------------------------------- kernel 3
// Flash attention, causal, no-max (bounded scores), exp2-domain Q.
// K-SPLIT: block = 256 thr / 4 waves; q-tile = 32 rows.
//   chain c = wave>>1: c=0 handles even 64-key tiles, c=1 odd tiles.
//   strip  s = wave&1: q rows [32qt+16s, 32qt+16s+16).
// Each chain has private LDS K/V tile; partials combined via LDS overlay.
// Pairing (p, 63-p) -> exactly 17 iterations per block; grid 1024 = 4 blk/CU.
__global__ __launch_bounds__(256, 4) void attn_kernel(
    const short* __restrict__ Q, const short* __restrict__ K,
    const short* __restrict__ Vt, short* __restrict__ O /* [T][E] bf16 */) {
  __shared__ __align__(16) char RAW[2 * 64 * 72 * 2 * 2];        // 36864 B
  short (*Ks)[64][72] = (short (*)[64][72])RAW;                  // [chain][k][d]
  short (*Vs)[64][72] = (short (*)[64][72])(RAW + 2 * 64 * 72 * 2);  // [chain][d][k]
  float (*Cb)[64][20] = (float (*)[64][20])RAW;                  // combine overlay

  const int tid = threadIdx.x;
  const int bid = blockIdx.x;  // 1024 = 32 pairs * 32 bh
  const int bh = bid & 31;     // bid%8 == bh%8 -> per-XCD K/V L2 locality
  const int pr = bid >> 5;     // 0..31
  const int b = bh >> 4, h = bh & 15;
  const long base = ((long)bh) << 17;  // bh * S*HD

  const int wave = tid >> 6, lane = tid & 63;
  const int c = wave >> 1;  // k-chain
  const int s = wave & 1;   // q-strip
  const int lrow = lane & 15, quad = lane >> 4;

  // staging: chain's 128 threads cover one 64x64 K tile and V^T tile
  const int ct = tid & 127;
  const int r0 = ct >> 1, chc = (ct & 1) * 32;
  const short* Kg = K + base + (long)r0 * HD_ + chc;
  const short* Vg = Vt + base + (long)r0 * S_ + chc;

  bf16x8 kreg[4], vreg[4];
  auto LD = [&](int k0) {
#pragma unroll
    for (int j = 0; j < 4; j++) {
      kreg[j] = *(const bf16x8*)(Kg + (long)k0 * HD_ + 8 * j);
      vreg[j] = *(const bf16x8*)(Vg + k0 + 8 * j);
    }
  };

  const int qts[2] = {pr, 63 - pr};
  LD(c * 64);
  bool nextld = false;

  for (int ph = 0; ph < 2; ph++) {
    const int qt = qts[ph];
    const int nkt = (qt >> 1) + 1;        // 64-key tiles covering this q-tile
    const int nc = (nkt + 1 - c) >> 1;    // tiles owned by this chain
    const int nit = (nkt + 1) >> 1;       // block-uniform iteration count
    if (ph == 1 && !nextld) LD(c * 64);

    const int qg = qt * 32 + s * 16 + lrow;
    const short* qp = Q + base + (long)qg * HD_;
    bf16x8 qf0 = *(const bf16x8*)(qp + quad * 8);
    bf16x8 qf1 = *(const bf16x8*)(qp + 32 + quad * 8);

    f32x4 Oacc[4];
#pragma unroll
    for (int db = 0; db < 4; db++) Oacc[db] = f32x4{0.f, 0.f, 0.f, 0.f};
    float lsum = 0.f;

    for (int i = 0; i < nit; i++) {
      const bool act = i < nc;
      const int kt = 2 * i + c;
      if (act) {
#pragma unroll
        for (int j = 0; j < 4; j++) {
          *(bf16x8*)&Ks[c][r0][chc + 8 * j] = kreg[j];
          *(bf16x8*)&Vs[c][r0][chc + 8 * j] = vreg[j];
        }
      }
      __syncthreads();
      // register prefetch for next tile (or next phase's first tile: k0=c*64)
      if (i + 1 < nc) {
        LD((2 * (i + 1) + c) * 64);
      } else if (ph == 0 && i + 1 == nc) {
        LD(c * 64);
        nextld = true;
      }

      if (act) {
        // S^T = K . Q^T
        f32x4 sc[4];
#pragma unroll
        for (int nb = 0; nb < 4; nb++) {
          bf16x8 ka0 = *(bf16x8*)&Ks[c][nb * 16 + lrow][quad * 8];
          bf16x8 ka1 = *(bf16x8*)&Ks[c][nb * 16 + lrow][32 + quad * 8];
          f32x4 acc = {0.f, 0.f, 0.f, 0.f};
          acc = __builtin_amdgcn_mfma_f32_16x16x32_bf16(ka0, qf0, acc, 0, 0, 0);
          acc = __builtin_amdgcn_mfma_f32_16x16x32_bf16(ka1, qf1, acc, 0, 0, 0);
          sc[nb] = acc;
        }

        // causal mask (last tile only can straddle the diagonal)
        if (kt == nkt - 1) {
          const int k0 = kt * 64;
#pragma unroll
          for (int nb = 0; nb < 4; nb++) {
            int kgl = k0 + nb * 16 + quad * 4;
#pragma unroll
            for (int r = 0; r < 4; r++)
              if (kgl + r > qg) sc[nb][r] = -1e30f;
          }
        }

        // exp2 + pack (int +0x8000 round, v_perm pair-pack) + raw lsum
        bf16x4 pf[4];
#pragma unroll
        for (int nb = 0; nb < 4; nb++) {
          unsigned u[4];
#pragma unroll
          for (int r = 0; r < 4; r++) {
            float p = __builtin_amdgcn_exp2f(sc[nb][r]);
            lsum += p;
            u[r] = __float_as_uint(p) + 0x8000u;
          }
          unsigned lo = __builtin_amdgcn_perm(u[1], u[0], 0x07060302u);
          unsigned hi = __builtin_amdgcn_perm(u[3], u[2], 0x07060302u);
          union { unsigned q[2]; bf16x4 v; } pk;
          pk.q[0] = lo; pk.q[1] = hi;
          pf[nb] = pk.v;
        }

        // O^T += V^T . P^T  (16x16x16 MFMA; V^T b128 frags via column perm)
#pragma unroll
        for (int p2 = 0; p2 < 2; p2++) {
#pragma unroll
          for (int db = 0; db < 4; db++) {
            bf16x8 vv = *(bf16x8*)&Vs[c][db * 16 + lrow][p2 * 32 + quad * 8];
            bf16x4 vlo = {vv[0], vv[1], vv[2], vv[3]};
            bf16x4 vhi = {vv[4], vv[5], vv[6], vv[7]};
            Oacc[db] = __builtin_amdgcn_mfma_f32_16x16x16bf16_1k(vlo, pf[2 * p2], Oacc[db], 0, 0, 0);
            Oacc[db] = __builtin_amdgcn_mfma_f32_16x16x16bf16_1k(vhi, pf[2 * p2 + 1], Oacc[db], 0, 0, 0);
          }
        }
      }
      __syncthreads();
    }

    // ---- combine chains (overlay on dead K/V LDS) ----
    if (c == 1) {
#pragma unroll
      for (int db = 0; db < 4; db++) {
        float4 o4 = make_float4(Oacc[db][0], Oacc[db][1], Oacc[db][2], Oacc[db][3]);
        *(float4*)&Cb[s][lane][db * 4] = o4;
      }
      Cb[s][lane][16] = lsum;
    }
    __syncthreads();
    if (c == 0) {
#pragma unroll
      for (int db = 0; db < 4; db++) {
        float4 o4 = *(float4*)&Cb[s][lane][db * 4];
        Oacc[db][0] += o4.x; Oacc[db][1] += o4.y;
        Oacc[db][2] += o4.z; Oacc[db][3] += o4.w;
      }
      lsum += Cb[s][lane][16];
      lsum += __shfl_xor(lsum, 16);
      lsum += __shfl_xor(lsum, 32);
      const float invl = 1.f / lsum;
      const long token = (long)b * S_ + qg;
      short* obase = O + token * E_ + h * HD_;
#pragma unroll
      for (int db = 0; db < 4; db++) {
        bf16x4 o;
#pragma unroll
        for (int r = 0; r < 4; r++) o[r] = f2bf(Oacc[db][r] * invl);
        *(bf16x4*)(obase + db * 16 + quad * 4) = o;
      }
    }
    __syncthreads();
  }
}

// ---------------------------------------------------------------- kernel 4
// out = attn(4096x1024 bf16) . proj_w^T + proj_b  -> fp32
// 128x64 tile (M x N), BK=32, grid 512 (2 blocks/CU), LDS double-buffer with
// register prefetch -> single barrier per K-iteration.
__global__ __launch_bounds__(256) void proj_kernel(
    const short* __restrict__ A, const short* __restrict__ W,
    const float* __restrict__ bias, float* __restrict__ out) {
  __shared__ short As[2][128][40];
  __shared__ short Bs[2][64][40];
  const int tid = threadIdx.x;
  const int bid = blockIdx.x;  // 512 = 32 (M/128) * 16 (N/64)
  const int m0 = (bid >> 4) * 128;
  const int n0 = (bid & 15) * 64;
  const int wave = tid >> 6, lane = tid & 63;
  const int wm = wave >> 1, wn = wave & 1;
  const int lrow = lane & 15, quad = lane >> 4;

  const int ar = tid >> 1, ac = (tid & 1) * 16;  // A staging: 128x32
  const int br = tid >> 2, bc = (tid & 3) * 8;   // B staging: 64x32

  bf16x8 a0, a1, b0;
  auto LDR = [&](int k0) {
    const short* ap = A + (long)(m0 + ar) * E_ + k0 + ac;
    a0 = *(const bf16x8*)(ap);
    a1 = *(const bf16x8*)(ap + 8);
    b0 = *(const bf16x8*)(W + (long)(n0 + br) * E_ + k0 + bc);
  };

  f32x4 acc[4][2];
#pragma unroll
  for (int i = 0; i < 4; i++)
#pragma unroll
    for (int j = 0; j < 2; j++) acc[i][j] = f32x4{0.f, 0.f, 0.f, 0.f};

  LDR(0);
  for (int kk = 0; kk < 32; kk++) {
    const int buf = kk & 1;
    *(bf16x8*)&As[buf][ar][ac] = a0;
    *(bf16x8*)&As[buf][ar][ac + 8] = a1;
    *(bf16x8*)&Bs[buf][br][bc] = b0;
    __syncthreads();
    if (kk < 31) LDR((kk + 1) * 32);

    bf16x8 af[4], bfr[2];
#pragma unroll
    for (int i = 0; i < 4; i++)
      af[i] = *(bf16x8*)&As[buf][wm * 64 + i * 16 + lrow][quad * 8];
#pragma unroll
    for (int j = 0; j < 2; j++)
      bfr[j] = *(bf16x8*)&Bs[buf][wn * 32 + j * 16 + lrow][quad * 8];
#pragma unroll
    for (int i = 0; i < 4; i++)
#pragma unroll
      for (int j = 0; j < 2; j++)
        acc[i][j] = __builtin_amdgcn_mfma_f32_16x16x32_bf16(af[i], bfr[j], acc[i][j], 0, 0, 0);
    // no second barrier: double-buffered
  }

#pragma unroll
  for (int j = 0; j < 2; j++) {
    int col = n0 + wn * 32 + j * 16 + lrow;
    float bv = bias[col];
#pragma unroll
    for (int i = 0; i < 4; i++) {
#pragma unroll
      for (int r = 0; r < 4; r++) {
        int row = m0 + wm * 64 + i * 16 + quad * 4 + r;
        out[(long)row * E_ + col] = acc[i][j][r] + bv;
      }
    }
  }
}

// ---------------------------------------------------------------- launch
extern "C" void kernel_launch(void* const* d_in, const int* in_sizes, int n_in,
                              void* d_out, int out_size, void* d_ws, size_t ws_size,
                              hipStream_t stream) {
  const float* x  = (const float*)d_in[0];
  const float* wq = (const float*)d_in[1];
  const float* bq = (const float*)d_in[2];
  const float* wk = (const float*)d_in[3];
  const float* bk = (const float*)d_in[4];
  const float* wv = (const float*)d_in[5];
  const float* bv = (const float*)d_in[6];
  const float* pw = (const float*)d_in[7];
  const float* pb = (const float*)d_in[8];
  float* out = (float*)d_out;

  char* ws = (char*)d_ws;
  const size_t qkv_bytes = (size_t)B_ * H_ * S_ * HD_ * 2;  // 8 MB each
  short* Qb = (short*)(ws);
  short* Kb = (short*)(ws + qkv_bytes);
  short* Vb = (short*)(ws + 2 * qkv_bytes);  // transposed [bh][d][s], perm'd
  short* AO = (short*)(ws + 3 * qkv_bytes);  // [T][E] bf16
  short* PW = (short*)(ws + 3 * qkv_bytes + (size_t)T_ * E_ * 2);

  qkv_conv_kernel<<<dim3(512 + 1024), dim3(256), 0, stream>>>(
      x, wq, bq, wk, bk, wv, bv, Qb, Kb, Vb, pw, PW);
  attn_kernel<<<dim3(32 * 32), dim3(256), 0, stream>>>(Qb, Kb, Vb, AO);
  proj_kernel<<<dim3(32 * 16), dim3(256), 0, stream>>>(AO, PW, pb, out);
}

// Round 5
// 146.618 us; speedup vs baseline: 1.0765x; 1.0765x over previous
//
#include <hip/hip_runtime.h>
#include <hip/hip_bf16.h>

// Problem constants (GPT2Attention classic): B=2, S=2048, E=1024, H=16, HD=64
#define B_ 2
#define S_ 2048
#define E_ 1024
#define H_ 16
#define HD_ 64
#define T_ (B_ * S_)  // 4096 tokens

typedef short bf16x8 __attribute__((ext_vector_type(8)));
typedef short bf16x4 __attribute__((ext_vector_type(4)));
typedef float f32x4 __attribute__((ext_vector_type(4)));

__device__ __forceinline__ short f2bf(float f) {
  union { float f; unsigned u; } v;
  v.f = f;
  unsigned r = v.u + 0x7fffu + ((v.u >> 16) & 1u);
  return (short)(r >> 16);
}

// KV blob: per (bh, 64-key tile) 8192 shorts = 16 KB, in MFMA fragment order.
//   K frags: g = nb*2+half (g in [0,8)):  blob[g*512 + lane*8 + j]
//            = K[k0 + nb*16 + (lane&15)][half*32 + (lane>>4)*8 + j]
//   V frags: g = p2*4+db:                 blob[4096 + g*512 + lane*8 + j]
//            = V[k0 + (2*p2 + (j>>2))*16 + (lane>>4)*4 + (j&3)][db*16 + (lane&15)]
// All attn LDS traffic is then lane*16B stride -> conflict-free b128.

// ---------------------------------------------------------------- kernel 1+2
// Merged: bid < 512 -> QKV projection; bid >= 512 -> proj_w fp32->bf16 convert.
// Q pre-scaled by 0.125*log2(e) (exp2 domain). Q -> [B,H,S,HD]; K,V -> blob.
__global__ __launch_bounds__(256) void qkv_conv_kernel(
    const float* __restrict__ x,
    const float* __restrict__ wq, const float* __restrict__ bq,
    const float* __restrict__ wk, const float* __restrict__ bk,
    const float* __restrict__ wv, const float* __restrict__ bv,
    short* __restrict__ Q, short* __restrict__ KV,
    const float* __restrict__ pw, short* __restrict__ pwb) {
  const int tid = threadIdx.x;
  if (blockIdx.x >= 512) {
    int i = ((blockIdx.x - 512) * 256 + tid) * 4;
    float4 f = *(const float4*)(pw + i);
    bf16x4 o;
    o[0] = f2bf(f.x); o[1] = f2bf(f.y); o[2] = f2bf(f.z); o[3] = f2bf(f.w);
    *(bf16x4*)(pwb + i) = o;
    return;
  }
  __shared__ short Xs[64][136];   // 64 tokens x 128 cols (2 heads)
  __shared__ short Ws[192][72];   // Wq|Wk|Wv rows
  __shared__ short Qt[64][68], Kt[64][68], Vt[64][68];

  const int bid = blockIdx.x;
  const int tb = bid >> 3, hg = bid & 7;   // token block, head group (2 heads)
  const int s0 = (tb * 64) & (S_ - 1);
  const int kt = s0 >> 6;                  // this token block's key-tile index
  const int bb = (tb * 64) >> 11;          // batch index
  const int wave = tid >> 6, lane = tid & 63;
  const int lrow = lane & 15, quad = lane >> 4;

  // stage x slice: 64 rows x 128 fp32 cols -> bf16
#pragma unroll
  for (int i = 0; i < 8; i++) {
    int c = tid + 256 * i;
    int row = c >> 5, col4 = c & 31;
    float4 f = *(const float4*)(x + ((long)(tb * 64 + row)) * E_ + hg * 128 + col4 * 4);
    bf16x4 o;
    o[0] = f2bf(f.x); o[1] = f2bf(f.y); o[2] = f2bf(f.z); o[3] = f2bf(f.w);
    *(bf16x4*)&Xs[row][col4 * 4] = o;
  }
#pragma unroll
  for (int m = 0; m < 3; m++) {
    const float* w = (m == 0) ? wq : (m == 1) ? wk : wv;
#pragma unroll
    for (int i = 0; i < 4; i++) {
      int c = tid + 256 * i;
      int row = m * 64 + (c >> 4), col = (c & 15) * 4;
      float4 f = *(const float4*)(w + (long)c * 4);
      bf16x4 o;
      o[0] = f2bf(f.x); o[1] = f2bf(f.y); o[2] = f2bf(f.z); o[3] = f2bf(f.w);
      *(bf16x4*)&Ws[row][col] = o;
    }
  }
  float bias[12];
#pragma unroll
  for (int nb = 0; nb < 12; nb++) {
    int sel = nb >> 2;
    int e = ((nb & 3) * 16) + lrow;
    bias[nb] = ((sel == 0) ? bq : (sel == 1) ? bk : bv)[e];
  }
  __syncthreads();

  bf16x8 bf0[12], bf1[12];
#pragma unroll
  for (int nb = 0; nb < 12; nb++) {
    bf0[nb] = *(bf16x8*)&Ws[nb * 16 + lrow][quad * 8];
    bf1[nb] = *(bf16x8*)&Ws[nb * 16 + lrow][32 + quad * 8];
  }

  const float QSCALE = 0.125f * 1.44269504089f;  // 1/sqrt(64) * log2(e)
  for (int hl = 0; hl < 2; hl++) {
    const int h = hg * 2 + hl;
    bf16x8 a0 = *(bf16x8*)&Xs[wave * 16 + lrow][hl * 64 + quad * 8];
    bf16x8 a1 = *(bf16x8*)&Xs[wave * 16 + lrow][hl * 64 + 32 + quad * 8];
#pragma unroll
    for (int nb = 0; nb < 12; nb++) {
      f32x4 acc = {0.f, 0.f, 0.f, 0.f};
      acc = __builtin_amdgcn_mfma_f32_16x16x32_bf16(a0, bf0[nb], acc, 0, 0, 0);
      acc = __builtin_amdgcn_mfma_f32_16x16x32_bf16(a1, bf1[nb], acc, 0, 0, 0);
      const int sel = nb >> 2;
      const float scale = (sel == 0) ? QSCALE : 1.0f;
      short (*ct)[68] = (sel == 0) ? Qt : (sel == 1) ? Kt : Vt;
#pragma unroll
      for (int r = 0; r < 4; r++) {
        ct[wave * 16 + quad * 4 + r][(nb & 3) * 16 + lrow] =
            f2bf((acc[r] + bias[nb]) * scale);
      }
    }
    __syncthreads();

    const int bh = bb * H_ + h;
    short* Qg = Q + ((long)bh * S_ + s0) * HD_;
    short* Tg = KV + ((long)(bh * 32 + kt)) * 8192;
    // Q rows (row-major, b128)
#pragma unroll
    for (int i = 0; i < 2; i++) {
      int c = tid + 256 * i;
      int row = c >> 3, col = (c & 7) * 8;
      *(bf16x8*)(Qg + (long)row * HD_ + col) = *(bf16x8*)&Qt[row][col];
    }
    // KV blob: thread writes chunks fid = tid + 256u (contiguous global)
#pragma unroll
    for (int u = 0; u < 4; u++) {
      int fid = tid + 256 * u;
      bf16x8 val;
      int lane2 = fid & 63;
      int quad2 = lane2 >> 4, lrow2 = lane2 & 15;
      if (u < 2) {  // K chunk
        int g = fid >> 6;
        int nb = g >> 1, half = g & 1;
        val = *(bf16x8*)&Kt[nb * 16 + lrow2][half * 32 + quad2 * 8];
      } else {      // V chunk (transpose gather)
        int g = (fid >> 6) & 7;
        int p2 = g >> 2, db = g & 3;
#pragma unroll
        for (int j = 0; j < 8; j++) {
          int key = (2 * p2 + (j >> 2)) * 16 + quad2 * 4 + (j & 3);
          val[j] = Vt[key][db * 16 + lrow2];
        }
      }
      *(bf16x8*)(Tg + fid * 8) = val;
    }
    __syncthreads();
  }
}

// ---------------------------------------------------------------- kernel 3
// Flash attention, causal, no-max (bounded scores), exp2-domain Q.
// Round-3 structure: 4 waves x 16 q-rows (64-row q-tile), pairs (p, 31-p)
// -> uniform 33 iterations; double-buffered LDS, 1 barrier/iter, register
// prefetch. KV arrives as fragment-blobs -> ALL LDS traffic conflict-free.
__global__ __launch_bounds__(256) void attn_kernel(
    const short* __restrict__ Q, const short* __restrict__ KV,
    short* __restrict__ O /* [T][E] bf16 */) {
  __shared__ short L[2][8192];  // [buf][ K 4096 | V 4096 ]

  const int tid = threadIdx.x;
  const int bid = blockIdx.x;      // 512 = 16 pairs * 32 bh
  const int bh = bid & 31;
  const int pr = bid >> 5;         // 0..15
  const int b = bh >> 4, h = bh & 15;
  const long qbase = ((long)bh) << 17;  // bh * S*HD

  const int wave = tid >> 6, lane = tid & 63;
  const int lrow = lane & 15, quad = lane >> 4;

  const short* Tg = KV + ((long)bh * 32) * 8192 + tid * 8;  // + kt*8192 + u*2048

  bf16x8 reg[4];
  auto LD = [&](int kt) {
    const short* p = Tg + (long)kt * 8192;
#pragma unroll
    for (int u = 0; u < 4; u++) reg[u] = *(const bf16x8*)(p + u * 2048);
  };

  const int qts[2] = {pr, 31 - pr};
  LD(0);
  int it = 0;
  for (int ph = 0; ph < 2; ph++) {
    const int qt = qts[ph];
    const int q0w = qt * 64 + wave * 16;
    const int qg = q0w + lrow;
    const short* qp = Q + qbase + (long)qg * HD_;
    bf16x8 qf0 = *(const bf16x8*)(qp + quad * 8);
    bf16x8 qf1 = *(const bf16x8*)(qp + 32 + quad * 8);

    f32x4 Oacc[4];
#pragma unroll
    for (int db = 0; db < 4; db++) Oacc[db] = f32x4{0.f, 0.f, 0.f, 0.f};
    float lsum = 0.f;

    const int nkt = qt + 1;
    for (int kt = 0; kt < nkt; kt++, it++) {
      const int buf = it & 1;
#pragma unroll
      for (int u = 0; u < 4; u++)
        *(bf16x8*)&L[buf][(tid + 256 * u) * 8] = reg[u];
      __syncthreads();

      // register prefetch for next tile (or next phase's tile 0)
      {
        int ktn = kt + 1;
        bool have = true;
        if (ktn == nkt) {
          if (ph == 0) ktn = 0; else have = false;
        }
        if (have) LD(ktn);
      }

      // S^T = K . Q^T  (conflict-free b128 fragment reads)
      f32x4 sc[4];
#pragma unroll
      for (int nb = 0; nb < 4; nb++) {
        bf16x8 ka0 = *(bf16x8*)&L[buf][(nb * 2 + 0) * 512 + lane * 8];
        bf16x8 ka1 = *(bf16x8*)&L[buf][(nb * 2 + 1) * 512 + lane * 8];
        f32x4 acc = {0.f, 0.f, 0.f, 0.f};
        acc = __builtin_amdgcn_mfma_f32_16x16x32_bf16(ka0, qf0, acc, 0, 0, 0);
        acc = __builtin_amdgcn_mfma_f32_16x16x32_bf16(ka1, qf1, acc, 0, 0, 0);
        sc[nb] = acc;
      }

      // causal mask (diagonal tile only)
      if (kt == qt) {
        const int k0 = kt * 64;
#pragma unroll
        for (int nb = 0; nb < 4; nb++) {
          int kgl = k0 + nb * 16 + quad * 4;
#pragma unroll
          for (int r = 0; r < 4; r++)
            if (kgl + r > qg) sc[nb][r] = -1e30f;
        }
      }

      // exp2 + integer-round pack + raw lsum
      bf16x4 pf[4];
#pragma unroll
      for (int nb = 0; nb < 4; nb++) {
        unsigned u[4];
#pragma unroll
        for (int r = 0; r < 4; r++) {
          float p = __builtin_amdgcn_exp2f(sc[nb][r]);
          lsum += p;
          u[r] = __float_as_uint(p) + 0x8000u;
        }
        unsigned lo = __builtin_amdgcn_perm(u[1], u[0], 0x07060302u);
        unsigned hi = __builtin_amdgcn_perm(u[3], u[2], 0x07060302u);
        union { unsigned q[2]; bf16x4 v; } pk;
        pk.q[0] = lo; pk.q[1] = hi;
        pf[nb] = pk.v;
      }

      // O^T += V^T . P^T (16x16x16 MFMA; conflict-free b128 V fragments)
#pragma unroll
      for (int p2 = 0; p2 < 2; p2++) {
#pragma unroll
        for (int db = 0; db < 4; db++) {
          bf16x8 vv = *(bf16x8*)&L[buf][4096 + (p2 * 4 + db) * 512 + lane * 8];
          bf16x4 vlo = {vv[0], vv[1], vv[2], vv[3]};
          bf16x4 vhi = {vv[4], vv[5], vv[6], vv[7]};
          Oacc[db] = __builtin_amdgcn_mfma_f32_16x16x16bf16_1k(vlo, pf[2 * p2], Oacc[db], 0, 0, 0);
          Oacc[db] = __builtin_amdgcn_mfma_f32_16x16x16bf16_1k(vhi, pf[2 * p2 + 1], Oacc[db], 0, 0, 0);
        }
      }
    }

    // epilogue for this q-tile
    lsum += __shfl_xor(lsum, 16);
    lsum += __shfl_xor(lsum, 32);
    const float invl = 1.f / lsum;
    const long token = (long)b * S_ + qg;
    short* obase = O + token * E_ + h * HD_;
#pragma unroll
    for (int db = 0; db < 4; db++) {
      bf16x4 o;
#pragma unroll
      for (int r = 0; r < 4; r++) o[r] = f2bf(Oacc[db][r] * invl);
      *(bf16x4*)(obase + db * 16 + quad * 4) = o;
    }
  }
}

// ---------------------------------------------------------------- kernel 4
// out = attn(4096x1024 bf16) . proj_w^T + proj_b  -> fp32
// 128x64 tile (M x N), BK=32, grid 512 (2 blocks/CU), LDS double-buffer with
// register prefetch -> single barrier per K-iteration.
__global__ __launch_bounds__(256) void proj_kernel(
    const short* __restrict__ A, const short* __restrict__ W,
    const float* __restrict__ bias, float* __restrict__ out) {
  __shared__ short As[2][128][40];
  __shared__ short Bs[2][64][40];
  const int tid = threadIdx.x;
  const int bid = blockIdx.x;  // 512 = 32 (M/128) * 16 (N/64)
  const int m0 = (bid >> 4) * 128;
  const int n0 = (bid & 15) * 64;
  const int wave = tid >> 6, lane = tid & 63;
  const int wm = wave >> 1, wn = wave & 1;
  const int lrow = lane & 15, quad = lane >> 4;

  const int ar = tid >> 1, ac = (tid & 1) * 16;  // A staging: 128x32
  const int br = tid >> 2, bc = (tid & 3) * 8;   // B staging: 64x32

  bf16x8 a0, a1, b0;
  auto LDR = [&](int k0) {
    const short* ap = A + (long)(m0 + ar) * E_ + k0 + ac;
    a0 = *(const bf16x8*)(ap);
    a1 = *(const bf16x8*)(ap + 8);
    b0 = *(const bf16x8*)(W + (long)(n0 + br) * E_ + k0 + bc);
  };

  f32x4 acc[4][2];
#pragma unroll
  for (int i = 0; i < 4; i++)
#pragma unroll
    for (int j = 0; j < 2; j++) acc[i][j] = f32x4{0.f, 0.f, 0.f, 0.f};

  LDR(0);
  for (int kk = 0; kk < 32; kk++) {
    const int buf = kk & 1;
    *(bf16x8*)&As[buf][ar][ac] = a0;
    *(bf16x8*)&As[buf][ar][ac + 8] = a1;
    *(bf16x8*)&Bs[buf][br][bc] = b0;
    __syncthreads();
    if (kk < 31) LDR((kk + 1) * 32);

    bf16x8 af[4], bfr[2];
#pragma unroll
    for (int i = 0; i < 4; i++)
      af[i] = *(bf16x8*)&As[buf][wm * 64 + i * 16 + lrow][quad * 8];
#pragma unroll
    for (int j = 0; j < 2; j++)
      bfr[j] = *(bf16x8*)&Bs[buf][wn * 32 + j * 16 + lrow][quad * 8];
#pragma unroll
    for (int i = 0; i < 4; i++)
#pragma unroll
      for (int j = 0; j < 2; j++)
        acc[i][j] = __builtin_amdgcn_mfma_f32_16x16x32_bf16(af[i], bfr[j], acc[i][j], 0, 0, 0);
  }

#pragma unroll
  for (int j = 0; j < 2; j++) {
    int col = n0 + wn * 32 + j * 16 + lrow;
    float bv = bias[col];
#pragma unroll
    for (int i = 0; i < 4; i++) {
#pragma unroll
      for (int r = 0; r < 4; r++) {
        int row = m0 + wm * 64 + i * 16 + quad * 4 + r;
        out[(long)row * E_ + col] = acc[i][j][r] + bv;
      }
    }
  }
}

// ---------------------------------------------------------------- launch
extern "C" void kernel_launch(void* const* d_in, const int* in_sizes, int n_in,
                              void* d_out, int out_size, void* d_ws, size_t ws_size,
                              hipStream_t stream) {
  const float* x  = (const float*)d_in[0];
  const float* wq = (const float*)d_in[1];
  const float* bq = (const float*)d_in[2];
  const float* wk = (const float*)d_in[3];
  const float* bk = (const float*)d_in[4];
  const float* wv = (const float*)d_in[5];
  const float* bv = (const float*)d_in[6];
  const float* pw = (const float*)d_in[7];
  const float* pb = (const float*)d_in[8];
  float* out = (float*)d_out;

  char* ws = (char*)d_ws;
  short* Qb = (short*)(ws);                                   // 8 MB
  short* KVb = (short*)(ws + (size_t)8 * 1024 * 1024);        // 16 MB blob
  short* AO = (short*)(ws + (size_t)24 * 1024 * 1024);        // [T][E] bf16, 8 MB
  short* PW = (short*)(ws + (size_t)32 * 1024 * 1024);        // 2 MB

  qkv_conv_kernel<<<dim3(512 + 1024), dim3(256), 0, stream>>>(
      x, wq, bq, wk, bk, wv, bv, Qb, KVb, pw, PW);
  attn_kernel<<<dim3(16 * 32), dim3(256), 0, stream>>>(Qb, KVb, AO);
  proj_kernel<<<dim3(32 * 16), dim3(256), 0, stream>>>(AO, PW, pb, out);
}